// Round 3
// baseline (46.188 us; speedup 1.0000x reference)
//
#include <hip/hip_runtime.h>
#include <math.h>

// Problem constants (from reference)
#define BROWS 262144
#define KCLS  101

__device__ __forceinline__ float groupReduceSum16(float v) {
    v += __shfl_xor(v, 1);
    v += __shfl_xor(v, 2);
    v += __shfl_xor(v, 4);
    v += __shfl_xor(v, 8);
    return v;
}

// One 16-lane group per row; 4 rows per wave64.
// Lane `sub` (0..15) owns contiguous elements j = sub*7 .. sub*7+6 (mask j>=101).
extern "C" __global__ void __launch_bounds__(256)
ord_main(const float* __restrict__ logit,
         const int*   __restrict__ labels,
         const float* __restrict__ cw,
         float*       __restrict__ partial)
{
    constexpr int K      = KCLS;
    constexpr int NCHUNK = BROWS / 4;          // 4 rows per wave-iteration

    const int tid  = threadIdx.x;
    const int lane = tid & 63;
    const int sub  = lane & 15;                // position within 16-lane group
    const int grp  = lane >> 4;                // group 0..3 within the wave
    const int wid  = tid >> 6;                 // wave index within block
    const int gw   = blockIdx.x * 4 + wid;     // global wave id (4 waves/block)
    const int nw   = gridDim.x * 4;

    const float inv_logK = 1.0f / logf(101.0f);   // folds at compile time
    const float invK     = 1.0f / 101.0f;
    const float eseScale = 1.0e-4f;               // (1/(K-1))^2
    const float uniScale = 0.75f * 0.01f;         // (ALPHA*W_UNI)/(K-1)

    float tacc = 0.0f;

    for (int c = gw; c < NCHUNK; c += nw) {
        const int row = c * 4 + grp;
        const float* rp = logit + (size_t)row * K;
        const int   y  = labels[row];
        const float wy = cw[y];
        const int base = sub * 7;

        // ---- load 7 contiguous elements ----
        float x[7];
#pragma unroll
        for (int t = 0; t < 7; ++t) {
            const int j = base + t;
            x[t] = (j < K) ? rp[j] : -3.0e38f;
        }

        // ---- row max (local + 4-step group butterfly) ----
        float mx = x[0];
#pragma unroll
        for (int t = 1; t < 7; ++t) mx = fmaxf(mx, x[t]);
        mx = fmaxf(mx, __shfl_xor(mx, 1));
        mx = fmaxf(mx, __shfl_xor(mx, 2));
        mx = fmaxf(mx, __shfl_xor(mx, 4));
        mx = fmaxf(mx, __shfl_xor(mx, 8));

        // ---- exp and sum ----
        float p[7];
        float sl = 0.0f;
#pragma unroll
        for (int t = 0; t < 7; ++t) {
            const int j = base + t;
            const float e = (j < K) ? __expf(x[t] - mx) : 0.0f;
            p[t] = e;
            sl  += e;
        }
        const float S   = groupReduceSum16(sl);
        const float inv = 1.0f / S;
#pragma unroll
        for (int t = 0; t < 7; ++t) p[t] *= inv;
        const float psum = sl * inv;          // this lane's probability mass

        // ---- exclusive prefix (CDF base) via 4-step inclusive lane scan ----
        float incl = psum;
        {
            float t1 = __shfl_up(incl, 1); if (sub >= 1) incl += t1;
            float t2 = __shfl_up(incl, 2); if (sub >= 2) incl += t2;
            float t4 = __shfl_up(incl, 4); if (sub >= 4) incl += t4;
            float t8 = __shfl_up(incl, 8); if (sub >= 8) incl += t8;
        }
        float cdf = incl - psum;              // exclusive prefix for j = base

        // next lane's first prob (for unimodal diff crossing lane boundary)
        const float pnext0 = __shfl_down(p[0], 1);

        // ---- per-element terms ----
        float ese = 0.f, emd = 0.f, tail = 0.f, uni = 0.f;
        float selL = 0.f, selY = 0.f, selR = 0.f;
#pragma unroll
        for (int t = 0; t < 7; ++t) {
            const int  j     = base + t;
            const bool valid = (j < K);
            const float pj = p[t];
            const float d  = (float)(j - y);

            ese  += pj * d * d;
            tail += (d * d > 2.5f) ? pj : 0.0f;      // |j-y| > 1

            cdf += pj;                               // inclusive cdf at j
            const float ct = (j <= y) ? 1.0f : 0.0f;
            const float df = cdf - ct;
            emd += valid ? df * df : 0.0f;

            const float pn    = (t < 6) ? p[t + 1] : pnext0;
            const float cdiff = (j < y) ? (pj - pn) : (pn - pj);
            uni += (j < K - 1) ? fmaxf(cdiff, 0.0f) : 0.0f;

            selY += (j == y)     ? pj : 0.0f;
            selL += (j == y - 1) ? pj : 0.0f;
            selR += (j == y + 1) ? pj : 0.0f;
        }

        // combine all linear terms with final weights BEFORE the reduce:
        // total = ce + 1.0*ese + 1.0*emd + 2.5*tail + 2.5*lpeak + 0.75*uni
        float acc = wy * eseScale * ese + invK * emd + 2.5f * tail + uniScale * uni;
        acc  = groupReduceSum16(acc);
        selY = groupReduceSum16(selY);
        selL = groupReduceSum16(selL);
        selR = groupReduceSum16(selR);

        const float logpy = __logf(selY);     // log p_y  (== logp_y)
        const float lp    = fmaxf(fmaxf(selL, selR) - selY + 0.25f, 0.0f);
        const float rowv  = acc + 2.5f * lp - wy * logpy * inv_logK;

        if (sub == 0) tacc += rowv;
    }

    // ---- block reduction (deterministic) ----
    tacc += __shfl_xor(tacc, 1);
    tacc += __shfl_xor(tacc, 2);
    tacc += __shfl_xor(tacc, 4);
    tacc += __shfl_xor(tacc, 8);
    tacc += __shfl_xor(tacc, 16);
    tacc += __shfl_xor(tacc, 32);

    __shared__ float sb[4];
    if (lane == 0) sb[wid] = tacc;
    __syncthreads();
    if (tid == 0) partial[blockIdx.x] = (sb[0] + sb[1]) + (sb[2] + sb[3]);
}

extern "C" __global__ void __launch_bounds__(256)
ord_final(const float* __restrict__ partial, float* __restrict__ out, int n)
{
    float v = 0.0f;
    for (int i = threadIdx.x; i < n; i += 256) v += partial[i];

    v += __shfl_xor(v, 1);
    v += __shfl_xor(v, 2);
    v += __shfl_xor(v, 4);
    v += __shfl_xor(v, 8);
    v += __shfl_xor(v, 16);
    v += __shfl_xor(v, 32);

    __shared__ float sb[4];
    const int lane = threadIdx.x & 63;
    const int wid  = threadIdx.x >> 6;
    if (lane == 0) sb[wid] = v;
    __syncthreads();
    if (threadIdx.x == 0)
        out[0] = ((sb[0] + sb[1]) + (sb[2] + sb[3])) * (1.0f / (float)BROWS);
}

extern "C" void kernel_launch(void* const* d_in, const int* in_sizes, int n_in,
                              void* d_out, int out_size, void* d_ws, size_t ws_size,
                              hipStream_t stream)
{
    const float* logit  = (const float*)d_in[0];
    const int*   labels = (const int*)d_in[1];
    const float* cw     = (const float*)d_in[2];
    float*       part   = (float*)d_ws;

    int NB = 2048;
    if ((size_t)NB * sizeof(float) > ws_size) NB = (int)(ws_size / sizeof(float));
    if (NB < 1) NB = 1;
    if (NB > 2048) NB = 2048;

    hipLaunchKernelGGL(ord_main, dim3(NB), dim3(256), 0, stream,
                       logit, labels, cw, part);
    hipLaunchKernelGGL(ord_final, dim3(1), dim3(256), 0, stream,
                       part, (float*)d_out, NB);
}